// Round 9
// baseline (183.225 us; speedup 1.0000x reference)
//
#include <hip/hip_runtime.h>
#include <cstdint>
#include <cstddef>

// Problem constants (from reference setup_inputs)
#define BB   8
#define NN   2048
#define DD   16
#define HHH  64
#define KK   32
#define CAP  96          // max within-R hits kept incl self (mean ~37, Poisson tail safe)
#define FCAP 48          // max fwd neighbors kept (<=32 barring exact d2 ties)
#define DT_C 0.01f
#define R2_C (0.08f * 0.08f)

// 2-D cell grid: 17x17 cells of size R, covering [-0.68, 0.68]^2 (clamped edges)
#define GRID 17
#define NCEL (GRID * GRID)           // 289
#define GOFF 0.68f
#define CINV 12.5f                   // 1/R
#define CSTRIDE 320                  // ints per batch in cellStart/hist/cursor

#define WPB   4                 // waves per block
#define BLOCK (WPB * 64)

// Same rounding as the reference's sum-of-squares (sub,sub,mul,mul,add; no fma).
__device__ __forceinline__ float dist2(float px, float py, float qx, float qy) {
    float dx = __fsub_rn(px, qx);
    float dy = __fsub_rn(py, qy);
    return __fadd_rn(__fmul_rn(dx, dx), __fmul_rn(dy, dy));
}

// tanh'(z) = 1 - tanh(z)^2 with tanh computed exactly like XLA-CPU's EmitTanh.
// STEP 0 only (feeds step-1 neighbor SELECTION). Numerics FROZEN.
__device__ __forceinline__ float dtanh_xla(float zz) {
    float xx = fminf(fmaxf(zz, -9.f), 9.f);
    float x2 = xx * xx;
    float p = fmaf(x2, -2.76076847742355e-16f, 2.00018790482477e-13f);
    p = fmaf(x2, p, -8.60467152213735e-11f);
    p = fmaf(x2, p, 5.12229709037114e-08f);
    p = fmaf(x2, p, 1.48572235717979e-05f);
    p = fmaf(x2, p, 6.37261928875436e-04f);
    p = fmaf(x2, p, 4.89352455891786e-03f);
    p = xx * p;
    float q = fmaf(x2, 1.19825839466702e-06f, 1.18534705686654e-04f);
    q = fmaf(x2, q, 2.26843463243900e-03f);
    q = fmaf(x2, q, 4.89352518554385e-03f);
    float r = __builtin_amdgcn_rcpf(q);
    float t = p * r;
    t = fmaf(fmaf(-q, t, p), r, t);      // one Newton step on the quotient
    return fmaf(-t, t, 1.0f);            // 1 - t^2
}

// Fast sech^2/4 for the FINAL step only (values feed only the output).
__device__ __forceinline__ float s2fast(float z) {
    float a = __builtin_amdgcn_exp2f(-2.885390082f * fabsf(z)); // e^{-2|z|}
    float b = 1.f + a;
    return a * __builtin_amdgcn_rcpf(b * b);
}

// v_mbcnt_lo/hi natively count set bits among lanes BELOW the caller: prefix count.
__device__ __forceinline__ int prefix_cnt(unsigned long long m) {
    return (int)__builtin_amdgcn_mbcnt_hi(
        (unsigned)(m >> 32), __builtin_amdgcn_mbcnt_lo((unsigned)m, 0u));
}

// batch = blk&7 (XCD-aware). Strided slot assignment (R7, neutral-but-harmless).
__device__ __forceinline__ int swizzled_slot(int blk, int w, int& bbase) {
    bbase = (blk & 7) << 11;
    return (blk >> 3) + (NN / WPB) * w;  // strided batch-local sorted slot
}

__device__ __forceinline__ int clampi(int v, int lo, int hi) {
    return v < lo ? lo : (v > hi ? hi : v);
}

// Cell id from a position — the ONE expression used by k_hist0, k_scatter and
// k_grad<true>'s fused histogram. Identical f32 ops on bit-identical inputs
// guarantee hist counts always match scatter's recomputed cids.
__device__ __forceinline__ int cell_id(float qx, float qy) {
    int cx = clampi((int)((qx + GOFF) * CINV), 0, GRID - 1);
    int cy = clampi((int)((qy + GOFF) * CINV), 0, GRID - 1);
    return cy * GRID + cx;
}

// 3x3 cell window of (px,py): three contiguous sorted ranges. Shared by k_cut/k_grad.
struct Win { int rs0, rl0, rs1, rl1, rs2, rl2, tot; };
__device__ __forceinline__ Win cell_window(const int* CS, float px, float py) {
    Win W;
    int cx = clampi((int)((px + GOFF) * CINV), 0, GRID - 1);
    int cy = clampi((int)((py + GOFF) * CINV), 0, GRID - 1);
    int xlo = cx > 0 ? cx - 1 : 0;
    int xhi = cx < GRID - 1 ? cx + 1 : GRID - 1;
    W.rs0 = 0; W.rl0 = 0; W.rs2 = 0; W.rl2 = 0;
    if (cy > 0) {
        int a = CS[(cy - 1) * GRID + xlo], b = CS[(cy - 1) * GRID + xhi + 1];
        W.rs0 = a; W.rl0 = b - a;
    }
    {
        int a = CS[cy * GRID + xlo], b = CS[cy * GRID + xhi + 1];
        W.rs1 = a; W.rl1 = b - a;
    }
    if (cy < GRID - 1) {
        int a = CS[(cy + 1) * GRID + xlo], b = CS[(cy + 1) * GRID + xhi + 1];
        W.rs2 = a; W.rl2 = b - a;
    }
    W.tot = W.rl0 + W.rl1 + W.rl2;
    return W;
}
__device__ __forceinline__ int win_map(const Win& W, int t) {
    int j = W.rs0 + t;
    int u1 = t - W.rl0;
    if (u1 >= 0) j = W.rs1 + u1;
    int u2 = u1 - W.rl1;
    if (u2 >= 0) j = W.rs2 + u2;
    return j;
}

// ---- Parallel binning (replaces the 8-block serial k_bin) ----
// k_hist0: 64 blocks x 256 (8 chunks/batch). LDS histogram -> global hist+cursor.
// Block 0 also computes v = W2 @ Wout (step-invariant, computed once per call;
// f32 fma chain ascending c == Eigen dot order -> bit-matches the reference).
__global__ __launch_bounds__(256) void k_hist0(
    const float* __restrict__ x,
    const float* __restrict__ W2, const float* __restrict__ Wout,
    int* __restrict__ hist, int* __restrict__ cursor, float* __restrict__ vOut) {
    __shared__ int lh[NCEL];
    int tid = threadIdx.x, blk = blockIdx.x;
    int bat = blk & 7, chunk = blk >> 3, bbase = bat << 11;
    int i = chunk * 256 + tid;                 // particle in [0,2048)
    for (int t = tid; t < NCEL; t += 256) lh[t] = 0;
    __syncthreads();
    float2 qq = *(const float2*)(x + (size_t)(bbase + i) * DD);
    atomicAdd(&lh[cell_id(qq.x, qq.y)], 1);
    if (blk == 0 && tid < HHH) {               // vArr (used by both steps)
        float acc = 0.f;
        for (int c = 0; c < 32; c++) acc = fmaf(W2[tid * 32 + c], Wout[c], acc);
        vOut[tid] = acc;
    }
    __syncthreads();
    for (int t = tid; t < NCEL; t += 256) {
        int v = lh[t];
        if (v) {
            atomicAdd(&hist[bat * CSTRIDE + t], v);
            atomicAdd(&cursor[bat * CSTRIDE + t], v);
        }
    }
}

// k_scatter: 64 blocks x 256. Each block redundantly prefix-scans its batch's
// READ-ONLY hist in LDS (no cross-block race), writes cellStart (chunk 0),
// then scatters via dst = base[cid] + (atomicSub(cursor)-1). Within-cell order
// is arbitrary — all downstream consumers are order-invariant (f64 sums,
// rank-by-value cutoff, value-compare selection); sortedPos are bit-copies.
template <bool FIRST>
__global__ __launch_bounds__(256) void k_scatter(
    const float* __restrict__ x, const float* __restrict__ pos,
    const int* __restrict__ hist, int* __restrict__ cursor,
    float2* __restrict__ sortedPos, unsigned short* __restrict__ sortedIdx,
    int* __restrict__ cellStart) {
    __shared__ int base[NCEL + 1];
    int tid = threadIdx.x, blk = blockIdx.x;
    int bat = blk & 7, chunk = blk >> 3, bbase = bat << 11;
    int i = chunk * 256 + tid;
    if (tid < 64) {             // wave 0: exclusive prefix over 289 bins, 5/lane
        int loc[5], s = 0;
#pragma unroll
        for (int k = 0; k < 5; ++k) {
            int idx = tid * 5 + k;
            loc[k] = (idx < NCEL) ? hist[bat * CSTRIDE + idx] : 0;
            s += loc[k];
        }
        int pre = s;
#pragma unroll
        for (int off = 1; off < 64; off <<= 1) {
            int t = __shfl_up(pre, off);
            if (tid >= off) pre += t;
        }
        pre -= s;               // exclusive prefix of this lane's first bin
#pragma unroll
        for (int k = 0; k < 5; ++k) {
            int idx = tid * 5 + k;
            if (idx <= NCEL) base[idx] = pre;
            pre += loc[k];
        }
    }
    __syncthreads();
    if (chunk == 0) {
        for (int t = tid; t <= NCEL; t += 256) cellStart[bat * CSTRIDE + t] = base[t];
    }
    float2 qq = FIRST ? *(const float2*)(x + (size_t)(bbase + i) * DD)
                      : *(const float2*)(pos + (size_t)(bbase + i) * 2);
    int cid = cell_id(qq.x, qq.y);
    int old = atomicSub(&cursor[bat * CSTRIDE + cid], 1);   // cursor self-zeroes
    int dst = base[cid] + (old - 1);
    sortedPos[bbase + dst] = qq;                             // verbatim bit-copy
    sortedIdx[bbase + dst] = (unsigned short)i;
}

// Kernel 1 per step — TWO particles per wave (slots p and p+1024); per-particle
// arithmetic sequence verbatim -> every Asp/Dsp/cutArr value bit-identical.
__global__ __launch_bounds__(BLOCK, 4) void k_cut(
    const float* __restrict__ x,
    const float2* __restrict__ sortedPos, const unsigned short* __restrict__ sortedIdx,
    const int* __restrict__ cellStart, const float* __restrict__ W1,
    float* __restrict__ cutArr,
    float* __restrict__ Asp, float* __restrict__ Dsp) {
    __shared__ float sD[WPB][2][CAP];       // two wave-private hit-d2 arrays

    int tid = threadIdx.x;
    int w = tid >> 6, lane = tid & 63;
    int bbase = (blockIdx.x & 7) << 11;
    int bat = bbase >> 11;
    int p = (blockIdx.x >> 3) + (NN / WPB / 2) * w;   // pair index in [0,1024)
    int sA = p, sB = p + (NN / 2);
    int gsA = bbase + sA, gsB = bbase + sB;

    // ---- A/D precompute for BOTH particles; W1 loads shared ----
    int jolA = (int)sortedIdx[gsA];
    int jolB = (int)sortedIdx[gsB];
    const float* xrowA = x + (size_t)(bbase + jolA) * DD;
    const float* xrowB = x + (size_t)(bbase + jolB) * DD;
    float xvA = (lane < DD) ? xrowA[lane] : 0.f;
    float xvB = (lane < DD) ? xrowB[lane] : 0.f;
    float pxA = __shfl(xvA, 0), pyA = __shfl(xvA, 1);
    float pxB = __shfl(xvB, 0), pyB = __shfl(xvB, 1);
    double AA0 = 0.0, AA1 = 0.0, AA2 = 0.0, AA3 = 0.0;
    double DA0 = 0.0, DA1 = 0.0, DA2 = 0.0, DA3 = 0.0;
    double AB0 = 0.0, AB1 = 0.0, AB2 = 0.0, AB3 = 0.0;
    double DB0 = 0.0, DB1 = 0.0, DB2 = 0.0, DB3 = 0.0;
#pragma unroll
    for (int f = 0; f < DD; f += 4) {
        float w0 = W1[(f + 0) * HHH + lane], w1 = W1[(f + 1) * HHH + lane];
        float w2 = W1[(f + 2) * HHH + lane], w3 = W1[(f + 3) * HHH + lane];
        float v0 = W1[(DD + f + 0) * HHH + lane], v1 = W1[(DD + f + 1) * HHH + lane];
        float v2 = W1[(DD + f + 2) * HHH + lane], v3 = W1[(DD + f + 3) * HHH + lane];
        float a0 = __shfl(xvA, f),     a1 = __shfl(xvA, f + 1);
        float a2 = __shfl(xvA, f + 2), a3 = __shfl(xvA, f + 3);
        float b0 = __shfl(xvB, f),     b1 = __shfl(xvB, f + 1);
        float b2 = __shfl(xvB, f + 2), b3 = __shfl(xvB, f + 3);
        AA0 = fma((double)a0, (double)w0, AA0);
        AA1 = fma((double)a1, (double)w1, AA1);
        AA2 = fma((double)a2, (double)w2, AA2);
        AA3 = fma((double)a3, (double)w3, AA3);
        DA0 = fma((double)a0, (double)v0, DA0);
        DA1 = fma((double)a1, (double)v1, DA1);
        DA2 = fma((double)a2, (double)v2, DA2);
        DA3 = fma((double)a3, (double)v3, DA3);
        AB0 = fma((double)b0, (double)w0, AB0);
        AB1 = fma((double)b1, (double)w1, AB1);
        AB2 = fma((double)b2, (double)w2, AB2);
        AB3 = fma((double)b3, (double)w3, AB3);
        DB0 = fma((double)b0, (double)v0, DB0);
        DB1 = fma((double)b1, (double)v1, DB1);
        DB2 = fma((double)b2, (double)v2, DB2);
        DB3 = fma((double)b3, (double)v3, DB3);
    }
    Asp[((size_t)gsA << 6) + lane] = (float)((AA0 + AA1) + (AA2 + AA3));
    Dsp[((size_t)gsA << 6) + lane] = (float)((DA0 + DA1) + (DA2 + DA3));
    Asp[((size_t)gsB << 6) + lane] = (float)((AB0 + AB1) + (AB2 + AB3));
    Dsp[((size_t)gsB << 6) + lane] = (float)((DB0 + DB1) + (DB2 + DB3));

    // ---- candidate scans (self included); same per-particle order ----
    const int* CS = cellStart + bat * CSTRIDE;
    Win WA = cell_window(CS, pxA, pyA);
    Win WB = cell_window(CS, pxB, pyB);

    auto scan = [&](float px, float py, const Win& W, float* sDrow) -> int {
        int cnt = 0;
        int t0 = lane, t1 = 64 + lane;
        bool in0 = t0 < W.tot, in1 = t1 < W.tot;
        int ja0 = in0 ? win_map(W, t0) : 0;
        float2 q0 = sortedPos[bbase + ja0];
        float2 q1;
        bool have1 = W.tot > 64;             // wave-uniform
        if (have1) {
            int ja1 = in1 ? win_map(W, t1) : 0;
            q1 = sortedPos[bbase + ja1];
        }
        float d2 = dist2(px, py, q0.x, q0.y);
        bool hit = in0 && (d2 < R2_C);
        unsigned long long m = __ballot(hit);
        int idx = cnt + prefix_cnt(m);
        if (hit && idx < CAP) sDrow[idx] = d2;
        cnt += (int)__popcll(m);
        if (have1) {
            float e2 = dist2(px, py, q1.x, q1.y);
            bool h2 = in1 && (e2 < R2_C);
            unsigned long long m2 = __ballot(h2);
            int i2 = cnt + prefix_cnt(m2);
            if (h2 && i2 < CAP) sDrow[i2] = e2;
            cnt += (int)__popcll(m2);
        }
        for (int c0 = 128; c0 < W.tot; c0 += 64) {   // rare residual
            int t = c0 + lane;
            int j = win_map(W, t);
            bool in = t < W.tot;
            float2 q = sortedPos[bbase + (in ? j : 0)];
            float dd = dist2(px, py, q.x, q.y);
            bool ht = in && (dd < R2_C);
            unsigned long long mm = __ballot(ht);
            int ix = cnt + prefix_cnt(mm);
            if (ht && ix < CAP) sDrow[ix] = dd;
            cnt += (int)__popcll(mm);
        }
        return cnt;
    };
    int cntA = scan(pxA, pyA, WA, sD[w][0]);
    int cntB = scan(pxB, pyB, WB, sD[w][1]);
    if (cntA > CAP) cntA = CAP;
    if (cntB > CAP) cntB = CAP;
    __threadfence_block();   // wave-local LDS RAW drain

    // ---- cutoffs = rank-KK values; combined bitonic hides chain latency ----
    const float INF = 1e30f;
    float cutoffA = R2_C, cutoffB = R2_C;
    bool bA = (cntA > KK + 1) && (cntA <= 64);
    bool bB = (cntB > KK + 1) && (cntB <= 64);
    if (bA || bB) {
        float vA = (bA && lane < cntA) ? sD[w][0][lane] : INF;
        float vB = (bB && lane < cntB) ? sD[w][1][lane] : INF;
#pragma unroll
        for (int k = 2; k <= 64; k <<= 1) {
#pragma unroll
            for (int j = k >> 1; j > 0; j >>= 1) {
                float pA = __shfl_xor(vA, j);
                float pB = __shfl_xor(vB, j);
                bool up = ((lane & k) == 0);
                bool takeMin = (((lane & j) == 0) == up);
                vA = takeMin ? fminf(vA, pA) : fmaxf(vA, pA);
                vB = takeMin ? fminf(vB, pB) : fmaxf(vB, pB);
            }
        }
        if (bA) cutoffA = __shfl(vA, KK);
        if (bB) cutoffB = __shfl(vB, KK);
    }
    // cnt in (64,96]: ~never, kept for correctness (original rank-count path)
#define BIGSEL(CNT, ROW, OUT)                                             \
    if ((CNT) > 64) {                                                     \
        float e0 = (lane < (CNT)) ? sD[w][ROW][lane] : INF;               \
        float e1 = (lane + 64 < (CNT)) ? sD[w][ROW][lane + 64] : INF;     \
        int r0 = 0, q0 = 0, r1 = 0, q1 = 0;                               \
        for (int k = 0; k < (CNT); k++) {                                 \
            float val = sD[w][ROW][k];                                    \
            r0 += (val < e0); q0 += (val == e0);                          \
            r1 += (val < e1); q1 += (val == e1);                          \
        }                                                                 \
        bool c0 = (r0 <= KK) && (r0 + q0 > KK);                           \
        bool c1 = (r1 <= KK) && (r1 + q1 > KK);                           \
        float cand = c0 ? e0 : (c1 ? e1 : INF);                           \
        _Pragma("unroll")                                                 \
        for (int off = 32; off; off >>= 1) cand = fminf(cand, __shfl_xor(cand, off)); \
        OUT = cand;                                                       \
    }
    BIGSEL(cntA, 0, cutoffA)
    BIGSEL(cntB, 1, cutoffB)
#undef BIGSEL
    if (lane == 0) {
        cutArr[gsA] = cutoffA;
        cutArr[gsB] = cutoffB;
    }
}

// Kernel 2 per step, one wave per SORTED slot s (lane = h).
// EXACT (step 0): dtanh_xla + f64 sums; also builds step-1's histogram from
// the freshly computed positions (lane 0: 2 global atomics — off critical path).
// !EXACT (final step): s2fast + f32 split accs.
template <bool EXACT>
__global__ __launch_bounds__(BLOCK, 4) void k_grad(
    const float* __restrict__ x, const unsigned short* __restrict__ sortedIdx,
    const float2* __restrict__ sortedPos, const int* __restrict__ cellStart,
    const float* __restrict__ cutArr,
    const float* __restrict__ Asp, const float* __restrict__ Dsp,
    const float* __restrict__ W1, const float* __restrict__ b1,
    const float* __restrict__ vArr,
    float* __restrict__ xOut, float* __restrict__ posOut,
    int* __restrict__ histN, int* __restrict__ curN) {
    __shared__ float sW1t[HHH * 33];                       // 8.25 KB
    __shared__ alignas(16) unsigned short sFwd[WPB][FCAP];
    __shared__ alignas(16) unsigned short sRev[WPB][CAP];
    __shared__ float sS[WPB][128];

    int tid = threadIdx.x;
    int w = tid >> 6, h = tid & 63;
    int bbase;
    int s = swizzled_slot(blockIdx.x, w, bbase);
    int bat = bbase >> 11;
    int gs = bbase + s;

    for (int t = tid; t < 2 * DD * HHH; t += BLOCK) {
        int f = t >> 6, hh = t & 63;
        sW1t[hh * 33 + f] = W1[t];            // pad 33: conflict-free write & read
    }
    __syncthreads();                          // the only block barrier

    float b1h = b1[h];
    float Apbs = Asp[((size_t)gs << 6) + h] + b1h;
    float Dpbs = Dsp[((size_t)gs << 6) + h] + b1h;
    float vh = vArr[h];

    float2 pp = sortedPos[gs];                // verbatim copy of own position
    float px = pp.x, py = pp.y;
    float cutp = cutArr[gs];

    // ---- inline scan: flags from bit-identical d2/cut compares, compacted ----
    const int* CS = cellStart + bat * CSTRIDE;
    Win W = cell_window(CS, px, py);
    int mf = 0, mr = 0;
#define PROC(IN, J, Q, CUTJ)                                              \
    {                                                                     \
        float d2 = dist2(px, py, (Q).x, (Q).y);                           \
        bool hit = (IN) && (d2 < R2_C) && ((J) != s);                     \
        bool fw = hit && (d2 <= cutp);                                    \
        bool rv = hit && (d2 <= (CUTJ));                                  \
        unsigned long long mF = __ballot(fw);                             \
        int iF = mf + prefix_cnt(mF);                                     \
        if (fw && iF < FCAP) sFwd[w][iF] = (unsigned short)(J);           \
        mf += (int)__popcll(mF);                                          \
        unsigned long long mR = __ballot(rv);                             \
        int iR = mr + prefix_cnt(mR);                                     \
        if (rv && iR < CAP) sRev[w][iR] = (unsigned short)(J);            \
        mr += (int)__popcll(mR);                                          \
    }
    {
        int t0 = h, t1 = 64 + h;
        bool in0 = t0 < W.tot, in1 = t1 < W.tot;
        int j0 = win_map(W, t0);
        int ja0 = in0 ? j0 : 0;
        float2 q0 = sortedPos[bbase + ja0];
        float cut0 = cutArr[bbase + ja0];
        bool have1 = W.tot > 64;              // wave-uniform
        int j1 = 0; float2 q1; float cut1 = 0.f;
        if (have1) {
            j1 = win_map(W, t1);
            int ja1 = in1 ? j1 : 0;
            q1 = sortedPos[bbase + ja1];
            cut1 = cutArr[bbase + ja1];
        }
        PROC(in0, j0, q0, cut0)
        if (have1) PROC(in1, j1, q1, cut1)
        for (int c0 = 128; c0 < W.tot; c0 += 64) {   // rare residual, original path
            int t = c0 + h;
            int j = win_map(W, t);
            bool in = t < W.tot;
            int ja = in ? j : 0;
            float2 q = sortedPos[bbase + ja];
            float cutj = cutArr[bbase + ja];
            PROC(in, j, q, cutj)
        }
    }
#undef PROC
    if (mf > FCAP) mf = FCAP;
    if (mr > CAP) mr = CAP;
    __threadfence_block();

    // ---- main loops: branch-free, 16-deep gather batching, scalar row bases ----
    const float* baseD = Dsp + ((size_t)bbase << 6);
    const float* baseA = Asp + ((size_t)bbase << 6);
    double T1 = 0.0, T2 = 0.0;                // EXACT: order-invariant accumulation
    float f1a = 0.f, f1b = 0.f, f2a = 0.f, f2b = 0.f;  // FAST: split f32 accs

#define TERM1(VAL)                                                        \
    { if constexpr (EXACT) T1 += (double)dtanh_xla(Apbs + (VAL));         \
      else { float sv_ = s2fast(Apbs + (VAL));                            \
             if (k & 1) f1b += sv_; else f1a += sv_; } }
#define TERM2(VAL)                                                        \
    { if constexpr (EXACT) T2 += (double)dtanh_xla(Dpbs + (VAL));         \
      else { float sv_ = s2fast(Dpbs + (VAL));                            \
             if (k & 1) f2b += sv_; else f2a += sv_; } }

#define UNPACK8(Q0, Q1, U)                                            \
    unsigned U[8];                                                    \
    U[0] = (unsigned)__builtin_amdgcn_readfirstlane(Q0.x);            \
    U[1] = (unsigned)__builtin_amdgcn_readfirstlane(Q0.y);            \
    U[2] = (unsigned)__builtin_amdgcn_readfirstlane(Q0.z);            \
    U[3] = (unsigned)__builtin_amdgcn_readfirstlane(Q0.w);            \
    U[4] = (unsigned)__builtin_amdgcn_readfirstlane(Q1.x);            \
    U[5] = (unsigned)__builtin_amdgcn_readfirstlane(Q1.y);            \
    U[6] = (unsigned)__builtin_amdgcn_readfirstlane(Q1.z);            \
    U[7] = (unsigned)__builtin_amdgcn_readfirstlane(Q1.w);

    {   // fwd stream
        const unsigned short* L = sFwd[w];
        int c = 0;
        for (; c + 16 <= mf; c += 16) {
            int4 q0 = *(const int4*)(L + c);
            int4 q1 = *(const int4*)(L + c + 8);
            UNPACK8(q0, q1, u)
            float d[16];
#pragma unroll
            for (int k = 0; k < 8; ++k) {     // 16 independent gathers in flight
                const float* ra = baseD + ((size_t)(u[k] & 0xffffu) << 6);
                const float* rb = baseD + ((size_t)(u[k] >> 16) << 6);
                d[2 * k]     = ra[h];
                d[2 * k + 1] = rb[h];
            }
#pragma unroll
            for (int k = 0; k < 16; ++k) TERM1(d[k])
        }
        for (; c + 8 <= mf; c += 8) {
            int4 q0 = *(const int4*)(L + c);
            UNPACK8(q0, q0, u)
            float d[8];
#pragma unroll
            for (int k = 0; k < 4; ++k) {
                const float* ra = baseD + ((size_t)(u[k] & 0xffffu) << 6);
                const float* rb = baseD + ((size_t)(u[k] >> 16) << 6);
                d[2 * k]     = ra[h];
                d[2 * k + 1] = rb[h];
            }
#pragma unroll
            for (int k = 0; k < 8; ++k) TERM1(d[k])
        }
        for (int k = 0; c < mf; ++c, k ^= 1) {
            unsigned jl = (unsigned)__builtin_amdgcn_readfirstlane((int)L[c]);
            TERM1((baseD + ((size_t)jl << 6))[h])
        }
    }
    {   // rev stream
        const unsigned short* L = sRev[w];
        int c = 0;
        for (; c + 16 <= mr; c += 16) {
            int4 q0 = *(const int4*)(L + c);
            int4 q1 = *(const int4*)(L + c + 8);
            UNPACK8(q0, q1, u)
            float d[16];
#pragma unroll
            for (int k = 0; k < 8; ++k) {
                const float* ra = baseA + ((size_t)(u[k] & 0xffffu) << 6);
                const float* rb = baseA + ((size_t)(u[k] >> 16) << 6);
                d[2 * k]     = ra[h];
                d[2 * k + 1] = rb[h];
            }
#pragma unroll
            for (int k = 0; k < 16; ++k) TERM2(d[k])
        }
        for (; c + 8 <= mr; c += 8) {
            int4 q0 = *(const int4*)(L + c);
            UNPACK8(q0, q0, u)
            float d[8];
#pragma unroll
            for (int k = 0; k < 4; ++k) {
                const float* ra = baseA + ((size_t)(u[k] & 0xffffu) << 6);
                const float* rb = baseA + ((size_t)(u[k] >> 16) << 6);
                d[2 * k]     = ra[h];
                d[2 * k + 1] = rb[h];
            }
#pragma unroll
            for (int k = 0; k < 8; ++k) TERM2(d[k])
        }
        for (int k = 0; c < mr; ++c, k ^= 1) {
            unsigned jl = (unsigned)__builtin_amdgcn_readfirstlane((int)L[c]);
            TERM2((baseA + ((size_t)jl << 6))[h])
        }
    }
#undef UNPACK8
#undef TERM1
#undef TERM2

    if constexpr (EXACT) {
        sS[w][h]      = vh * (float)T1;
        sS[w][64 + h] = vh * (float)T2;
    } else {
        float vh4 = 4.f * vh;                 // sech^2 = 4 * s2fast
        sS[w][h]      = vh4 * (f1a + f1b);
        sS[w][64 + h] = vh4 * (f2a + f2b);
    }
    __threadfence_block();                    // wave-local: no block barrier needed

    // full-wave tail: pair (l, l+32) splits each 64-term dot in half.
    float g;
    {
        int col = h & 31;                     // output column (16 fwd + 16 rev)
        const float* Sv = &sS[w][(col < 16) ? 0 : 64];
        int hh0 = (h < 32) ? 0 : 32;          // which half of the 64 terms
        if constexpr (EXACT) {
            double a0 = 0.0, a1 = 0.0, a2 = 0.0, a3 = 0.0;
            for (int hh = hh0; hh < hh0 + 32; hh += 4) {
                a0 = fma((double)sW1t[(hh + 0) * 33 + col], (double)Sv[hh + 0], a0);
                a1 = fma((double)sW1t[(hh + 1) * 33 + col], (double)Sv[hh + 1], a1);
                a2 = fma((double)sW1t[(hh + 2) * 33 + col], (double)Sv[hh + 2], a2);
                a3 = fma((double)sW1t[(hh + 3) * 33 + col], (double)Sv[hh + 3], a3);
            }
            double gd = (a0 + a1) + (a2 + a3);
            double go = __shfl_xor(gd, 32);   // partner half
            g = (float)(gd + go);
        } else {
            float a0 = 0.f, a1 = 0.f, a2 = 0.f, a3 = 0.f;
            for (int hh = hh0; hh < hh0 + 32; hh += 4) {
                a0 = fmaf(sW1t[(hh + 0) * 33 + col], Sv[hh + 0], a0);
                a1 = fmaf(sW1t[(hh + 1) * 33 + col], Sv[hh + 1], a1);
                a2 = fmaf(sW1t[(hh + 2) * 33 + col], Sv[hh + 2], a2);
                a3 = fmaf(sW1t[(hh + 3) * 33 + col], Sv[hh + 3], a3);
            }
            float gd = (a0 + a1) + (a2 + a3);
            float go = __shfl_xor(gd, 32);    // partner half
            g = gd + go;
        }
    }
    float g2 = __shfl(g, (h + 16) & 63);
    int jo = (int)sortedIdx[gs];              // original batch-local id (uniform)
    float xn = 0.f;
    if (h < DD) {
        size_t prow = (size_t)(bbase + jo) * DD;
        // mirror reference: mul (DT*grad) then sub; block FMA contraction
        xn = __fsub_rn(x[prow + h], __fmul_rn(DT_C, __fadd_rn(g, g2)));
        xOut[prow + h] = xn;
        if (h < 2) posOut[(bbase + jo) * 2 + h] = xn;
    }
    if constexpr (EXACT) {                    // fused step-1 histogram build
        float pyn = __shfl(xn, 1);            // all lanes execute; lane1 data valid
        if (h == 0) {
            int c = cell_id(xn, pyn);         // same expr as k_scatter's recompute
            atomicAdd(&histN[bat * CSTRIDE + c], 1);
            atomicAdd(&curN[bat * CSTRIDE + c], 1);
        }
    }
}

extern "C" void kernel_launch(void* const* d_in, const int* in_sizes, int n_in,
                              void* d_out, int out_size, void* d_ws, size_t ws_size,
                              hipStream_t stream) {
    const float* x0   = (const float*)d_in[0];
    const float* W1   = (const float*)d_in[1];
    const float* b1   = (const float*)d_in[2];
    const float* W2   = (const float*)d_in[3];
    const float* Wout = (const float*)d_in[5];
    float* out = (float*)d_out;

    // workspace layout (floats); total ~10 MB + 40 KB bin metadata
    float* ws   = (float*)d_ws;
    float* posA = ws;                        // 32768 (dead sink for last step)
    float* posB = posA + 32768;              // 32768
    float* x1   = posB + 32768;              // 262144
    float* Asp  = x1 + 262144;               // 16384*64 (4 MB, unscaled)
    float* Dsp  = Asp + 16384 * 64;          // 16384*64 (4 MB, unscaled)
    float* cut  = Dsp + 16384 * 64;          // 16384
    float2* sPosS = (float2*)(cut + 16384);                               // 16384 float2
    unsigned short* sIdx = (unsigned short*)(sPosS + 16384);              // 16384
    int* cellStart = (int*)(sIdx + 16384);                                // 8*320
    float* vArr = (float*)(cellStart + BB * CSTRIDE);                     // 64
    int* binMeta = (int*)(vArr + 64);        // hist0|cur0|hist1|cur1, 4*2560 ints
    int* hist0 = binMeta;
    int* cur0  = binMeta + BB * CSTRIDE;
    int* hist1 = binMeta + 2 * BB * CSTRIDE;
    int* cur1  = binMeta + 3 * BB * CSTRIDE;

    const int NB  = (BB * NN) / WPB;         // 4096 blocks x 256 thr (k_grad)
    const int NBC = (BB * NN) / (WPB * 2);   // 2048 blocks x 256 thr (k_cut)
    const int NBS = (BB * NN) / 256;         // 64 blocks x 256 thr (hist/scatter)

    // zero bin metadata (cursors self-zero, hists don't; 40 KB, graph-safe)
    hipMemsetAsync(binMeta, 0, 4 * BB * CSTRIDE * sizeof(int), stream);

    // step 0: x0 -> x1  (EXACT: x1 feeds step-1 neighbor selection)
    k_hist0<<<NBS, 256, 0, stream>>>(x0, W2, Wout, hist0, cur0, vArr);
    k_scatter<true><<<NBS, 256, 0, stream>>>(x0, nullptr, hist0, cur0,
                                             sPosS, sIdx, cellStart);
    k_cut<<<NBC, BLOCK, 0, stream>>>(x0, sPosS, sIdx, cellStart, W1, cut, Asp, Dsp);
    k_grad<true><<<NB, BLOCK, 0, stream>>>(x0, sIdx, sPosS, cellStart, cut, Asp, Dsp,
                                           W1, b1, vArr, x1, posB, hist1, cur1);
    // step 1: x1 -> out  (FAST: values feed only the output; hist1 built above)
    k_scatter<false><<<NBS, 256, 0, stream>>>(nullptr, posB, hist1, cur1,
                                              sPosS, sIdx, cellStart);
    k_cut<<<NBC, BLOCK, 0, stream>>>(x1, sPosS, sIdx, cellStart, W1, cut, Asp, Dsp);
    k_grad<false><<<NB, BLOCK, 0, stream>>>(x1, sIdx, sPosS, cellStart, cut, Asp, Dsp,
                                            W1, b1, vArr, out, posA,
                                            nullptr, nullptr);
}